// Round 4
// baseline (1053.956 us; speedup 1.0000x reference)
//
#include <hip/hip_runtime.h>

#define EPS_BN 1e-4f
constexpr int BLK = 256;
constexpr int ECAPF = 512;    // fine tile pair cap (expect ~88)
constexpr int ECAPC = 1024;   // coarse tile pair cap (expect ~245)

// ---------- fine rulebook: subm pairs grouped by k + up pairs grouped by offset ----------
// 64 threads = 1 wave per block. entry = (r<<25) | j
__global__ __launch_bounds__(64) void build_fine_k(
    const int* __restrict__ nbr, const int* __restrict__ parent,
    const int* __restrict__ offid, int n, int ecap,
    int* __restrict__ seg, int* __restrict__ ent,
    int* __restrict__ segu, int* __restrict__ entu) {
  int T = blockIdx.x, r = threadIdx.x;
  int i = T * 64 + r;
  bool valid = i < n;
  int base = 0;
  if (r == 0) seg[T * 28] = 0;
#pragma unroll 1
  for (int k = 0; k < 27; ++k) {
    int j = valid ? nbr[(size_t)i * 27 + k] : -1;
    bool act = j >= 0;
    unsigned long long mb = __ballot(act);
    int pre = __popcll(mb & ((1ull << r) - 1));
    if (act && base + pre < ecap)
      ent[(size_t)T * ecap + base + pre] = (r << 25) | j;
    base += __popcll(mb);
    if (r == 0) seg[T * 28 + k + 1] = base;
  }
  // up rulebook: rows grouped by own offset; j = parent
  int o = valid ? offid[i] : -1;
  int pa = valid ? parent[i] : 0;
  base = 0;
  if (r == 0) segu[T * 9] = 0;
#pragma unroll 1
  for (int oo = 0; oo < 8; ++oo) {
    bool act = o == oo;
    unsigned long long mb = __ballot(act);
    int pre = __popcll(mb & ((1ull << r) - 1));
    if (act) entu[(size_t)T * 64 + base + pre] = (r << 25) | pa;
    base += __popcll(mb);
    if (r == 0) segu[T * 9 + oo + 1] = base;
  }
}

// coarse subm rulebook only
__global__ __launch_bounds__(64) void build_subm_k(
    const int* __restrict__ nbr, int n, int ecap,
    int* __restrict__ seg, int* __restrict__ ent) {
  int T = blockIdx.x, r = threadIdx.x;
  int i = T * 64 + r;
  bool valid = i < n;
  int base = 0;
  if (r == 0) seg[T * 28] = 0;
#pragma unroll 1
  for (int k = 0; k < 27; ++k) {
    int j = valid ? nbr[(size_t)i * 27 + k] : -1;
    bool act = j >= 0;
    unsigned long long mb = __ballot(act);
    int pre = __popcll(mb & ((1ull << r) - 1));
    if (act && base + pre < ecap)
      ent[(size_t)T * ecap + base + pre] = (r << 25) | j;
    base += __popcll(mb);
    if (r == 0) seg[T * 28 + k + 1] = base;
  }
}

__global__ __launch_bounds__(BLK) void child_scatter_k(
    const int* __restrict__ parent, const int* __restrict__ offid, int n,
    int* __restrict__ ccnt, int* __restrict__ cent) {
  int i = blockIdx.x * BLK + threadIdx.x;
  if (i >= n) return;
  int p = parent[i];
  int slot = atomicAdd(&ccnt[p], 1);
  cent[p * 8 + slot] = i | (offid[i] << 25);
}

__global__ __launch_bounds__(64) void build_down_k(
    const int* __restrict__ ccnt, const int* __restrict__ cent, int nc,
    int* __restrict__ segd, int* __restrict__ entd) {
  int T = blockIdx.x, r = threadIdx.x;
  int p = T * 64 + r;
  bool valid = p < nc;
  int cn = valid ? ccnt[p] : 0;
  int e[8];
#pragma unroll
  for (int s = 0; s < 8; ++s) e[s] = s < cn ? cent[p * 8 + s] : -1;
  int base = 0;
  if (r == 0) segd[T * 9] = 0;
#pragma unroll 1
  for (int oo = 0; oo < 8; ++oo) {
#pragma unroll
    for (int s = 0; s < 8; ++s) {
      bool act = e[s] >= 0 && (e[s] >> 25) == oo;
      unsigned long long mb = __ballot(act);
      int pre = __popcll(mb & ((1ull << r) - 1));
      if (act) entd[(size_t)T * 512 + base + pre] = (r << 25) | (e[s] & 0x1FFFFFF);
      base += __popcll(mb);
    }
    if (r == 0) segd[T * 9 + oo + 1] = base;
  }
}

// ---------- tiled conv v2: LDS acc, W double-buffered, X direct from L2, fused BN-finalize + stats ----------
template <int CI, int CO, int KT, bool CAT>
__global__ __launch_bounds__(BLK) void tconv_k(
    const float* __restrict__ inA, const float* __restrict__ inB,
    const int* __restrict__ seg, const int* __restrict__ ent, int ecap,
    const float* __restrict__ sumsA, const float* __restrict__ gA,
    const float* __restrict__ bA, float invA,
    const float* __restrict__ sumsB, const float* __restrict__ gB,
    const float* __restrict__ bB, float invB,
    const float* __restrict__ W, float* __restrict__ out, int n,
    float* __restrict__ osums) {
  constexpr int GO = CO / 16;
  constexpr int AP = CO + 4;
  constexpr int WSZ = CI * CO;
  constexpr int WL = WSZ / 4 / BLK;
  __shared__ float lw[2][WSZ];
  __shared__ float lacc[64 * AP];
  __shared__ float lst[2 * CI];
  int t = threadIdx.x;
  int T = blockIdx.x;

  // fused BN finalize -> lst = [scale[CI], shift[CI]]
  if constexpr (CAT) {
    if (t < CI / 2) {
      float mu = sumsA[t] * invA, var = sumsA[CI / 2 + t] * invA - mu * mu;
      float sc = gA[t] / sqrtf(var + EPS_BN);
      lst[t] = sc; lst[CI + t] = bA[t] - mu * sc;
    } else if (t < CI) {
      int c = t - CI / 2;
      float mu = sumsB[c] * invB, var = sumsB[CI / 2 + c] * invB - mu * mu;
      float sc = gB[c] / sqrtf(var + EPS_BN);
      lst[t] = sc; lst[CI + t] = bB[c] - mu * sc;
    }
  } else {
    if (t < CI) {
      float mu = sumsA[t] * invA, var = sumsA[CI + t] * invA - mu * mu;
      float sc = gA[t] / sqrtf(var + EPS_BN);
      lst[t] = sc; lst[CI + t] = bA[t] - mu * sc;
    }
  }
  for (int idx = t; idx < 64 * AP; idx += BLK) lacc[idx] = 0.f;

  const int* segT = seg + T * (KT + 1);
  const int* entT = ent + (size_t)T * ecap;

  // first nonempty phase
  int k = KT, e0 = 0, e1 = 0;
  {
    int prev = segT[0];
#pragma unroll 1
    for (int q = 0; q < KT; ++q) {
      int cur = segT[q + 1];
      if (cur > prev) { k = q; e0 = prev; e1 = cur; break; }
      prev = cur;
    }
  }
  if (k < KT) {
    const float4* wsrc = reinterpret_cast<const float4*>(W + (size_t)k * WSZ);
#pragma unroll
    for (int q = 0; q < WL; ++q)
      reinterpret_cast<float4*>(lw[0])[t + q * BLK] = wsrc[t + q * BLK];
  }
  __syncthreads();

  int par = 0;
#pragma unroll 1
  while (k < KT) {
    // scan next nonempty phase
    int kn = KT, f0 = 0, f1 = 0;
    {
      int prev = e1;
#pragma unroll 1
      for (int q = k + 1; q < KT; ++q) {
        int cur = segT[q + 1];
        if (cur > prev) { kn = q; f0 = prev; f1 = cur; break; }
        prev = cur;
      }
    }
    // prefetch W[kn] into registers
    float4 wreg[WL];
    if (kn < KT) {
      const float4* wsrc = reinterpret_cast<const float4*>(W + (size_t)kn * WSZ);
#pragma unroll
      for (int q = 0; q < WL; ++q) wreg[q] = wsrc[t + q * BLK];
    }
    // compute phase k
    int ee0 = min(e0, ecap), ee1 = min(e1, ecap);
    int m = ee1 - ee0;
    int s = t >> 4, g = (t & 15) * GO;
    const float* wp = lw[par];
#pragma unroll 1
    for (int p0 = 0; p0 < m; p0 += 16) {
      int p = p0 + s;
      if (p < m) {
        int e = entT[ee0 + p];
        int r = e >> 25, j = e & 0x1FFFFFF;
        float acc[GO];
#pragma unroll
        for (int b = 0; b < GO; ++b) acc[b] = 0.f;
#pragma unroll
        for (int c4 = 0; c4 < CI / 4; ++c4) {
          int cb = c4 * 4;
          float4 x;
          if constexpr (CAT) {
            if (cb < CI / 2) x = *reinterpret_cast<const float4*>(inA + (size_t)j * (CI / 2) + cb);
            else             x = *reinterpret_cast<const float4*>(inB + (size_t)j * (CI / 2) + (cb - CI / 2));
          } else {
            x = *reinterpret_cast<const float4*>(inA + (size_t)j * CI + cb);
          }
          float xs[4] = {x.x, x.y, x.z, x.w};
#pragma unroll
          for (int q = 0; q < 4; ++q) {
            float y = fmaf(xs[q], lst[cb + q], lst[CI + cb + q]);
            y = y > 0.f ? y : 0.f;
            const float* wr = wp + (cb + q) * CO + g;
            if constexpr (GO == 4) {
              float4 wv = *reinterpret_cast<const float4*>(wr);
              acc[0] = fmaf(y, wv.x, acc[0]);
              acc[1] = fmaf(y, wv.y, acc[1]);
              acc[2] = fmaf(y, wv.z, acc[2]);
              acc[3] = fmaf(y, wv.w, acc[3]);
            } else {
              float2 wv = *reinterpret_cast<const float2*>(wr);
              acc[0] = fmaf(y, wv.x, acc[0]);
              acc[1] = fmaf(y, wv.y, acc[1]);
            }
          }
        }
        float* ap = &lacc[r * AP + g];
        if constexpr (GO == 4) {
          float4 o = *reinterpret_cast<float4*>(ap);
          *reinterpret_cast<float4*>(ap) =
              make_float4(o.x + acc[0], o.y + acc[1], o.z + acc[2], o.w + acc[3]);
        } else {
          float2 o = *reinterpret_cast<float2*>(ap);
          *reinterpret_cast<float2*>(ap) = make_float2(o.x + acc[0], o.y + acc[1]);
        }
      }
    }
    // write prefetched W to alternate buffer
    if (kn < KT) {
#pragma unroll
      for (int q = 0; q < WL; ++q)
        reinterpret_cast<float4*>(lw[par ^ 1])[t + q * BLK] = wreg[q];
    }
    __syncthreads();
    par ^= 1; k = kn; e0 = f0; e1 = f1;
  }

  // epilogue: coalesced store + fused per-channel stats
  for (int idx = t; idx < 64 * (CO / 4); idx += BLK) {
    int r = idx / (CO / 4), c4 = idx - r * (CO / 4);
    int row = T * 64 + r;
    if (row < n)
      *reinterpret_cast<float4*>(out + (size_t)row * CO + c4 * 4) =
          *reinterpret_cast<const float4*>(&lacc[r * AP + c4 * 4]);
  }
  if (t < CO) {
    float s = 0.f, ss = 0.f;
#pragma unroll 4
    for (int r = 0; r < 64; ++r) {
      float x = lacc[r * AP + t];
      s += x; ss = fmaf(x, x, ss);
    }
    atomicAdd(&osums[t], s);
    atomicAdd(&osums[CO + t], ss);
  }
}

// ---------------- conv_in: [N,3] x [27,3,32] -> [N,32], fused stats ----------------
__global__ __launch_bounds__(BLK) void conv_in_k(
    const float* __restrict__ feat, const int* __restrict__ nbr,
    const float* __restrict__ W, float* __restrict__ out, int n,
    float* __restrict__ osums) {
  int i = blockIdx.x * BLK + threadIdx.x;
  bool valid = i < n;
  float acc[32];
#pragma unroll
  for (int c = 0; c < 32; ++c) acc[c] = 0.f;
#pragma unroll 1
  for (int k = 0; k < 27; ++k) {
    int j = valid ? nbr[(size_t)i * 27 + k] : -1;
    if (j < 0) continue;
    float x0 = feat[j * 3 + 0], x1 = feat[j * 3 + 1], x2 = feat[j * 3 + 2];
    const float* w0 = W + k * 96;
#pragma unroll
    for (int co = 0; co < 8; ++co) {
      float4 a = *reinterpret_cast<const float4*>(w0 + co * 4);
      float4 b = *reinterpret_cast<const float4*>(w0 + 32 + co * 4);
      float4 cc = *reinterpret_cast<const float4*>(w0 + 64 + co * 4);
      acc[4*co+0] = fmaf(x0, a.x, fmaf(x1, b.x, fmaf(x2, cc.x, acc[4*co+0])));
      acc[4*co+1] = fmaf(x0, a.y, fmaf(x1, b.y, fmaf(x2, cc.y, acc[4*co+1])));
      acc[4*co+2] = fmaf(x0, a.z, fmaf(x1, b.z, fmaf(x2, cc.z, acc[4*co+2])));
      acc[4*co+3] = fmaf(x0, a.w, fmaf(x1, b.w, fmaf(x2, cc.w, acc[4*co+3])));
    }
  }
  if (valid) {
    float* o = out + (size_t)i * 32;
#pragma unroll
    for (int co = 0; co < 8; ++co)
      *reinterpret_cast<float4*>(o + co * 4) = make_float4(acc[4*co], acc[4*co+1], acc[4*co+2], acc[4*co+3]);
  }
  // fused stats: wave shuffle reduce -> per-block atomic
  __shared__ float red[2][4][32];
  int w = threadIdx.x >> 6;
#pragma unroll
  for (int c = 0; c < 32; ++c) {
    float v = acc[c], q = acc[c] * acc[c];
#pragma unroll
    for (int off = 32; off; off >>= 1) {
      v += __shfl_down(v, off);
      q += __shfl_down(q, off);
    }
    if ((threadIdx.x & 63) == 0) { red[0][w][c] = v; red[1][w][c] = q; }
  }
  __syncthreads();
  if (threadIdx.x < 64) {
    int kind = threadIdx.x >> 5, c = threadIdx.x & 31;
    float s = red[kind][0][c] + red[kind][1][c] + red[kind][2][c] + red[kind][3][c];
    atomicAdd(&osums[kind * 32 + c], s);
  }
}

// ---------------- head: finalize + bn(f3) @ w_lin + b_lin -> [N,50] ----------------
__global__ __launch_bounds__(BLK) void head_k(
    const float* __restrict__ fin, const float* __restrict__ sums,
    const float* __restrict__ gm, const float* __restrict__ bt, float inv_n,
    const float* __restrict__ Wl, const float* __restrict__ bl,
    float* __restrict__ out, int n) {
  __shared__ float lw[32 * 50];
  __shared__ float lb[52];
  __shared__ float lst[64];
  int t = threadIdx.x;
  if (t < 32) {
    float mu = sums[t] * inv_n, var = sums[32 + t] * inv_n - mu * mu;
    float sc = gm[t] / sqrtf(var + EPS_BN);
    lst[t] = sc; lst[32 + t] = bt[t] - mu * sc;
  }
  for (int idx = t; idx < 1600; idx += BLK) lw[idx] = Wl[idx];
  if (t < 50) lb[t] = bl[t];
  __syncthreads();
  int i = blockIdx.x * BLK + t;
  if (i >= n) return;
  float x[32];
  const float* fj = fin + (size_t)i * 32;
#pragma unroll
  for (int c4 = 0; c4 < 8; ++c4) {
    float4 v = *reinterpret_cast<const float4*>(fj + c4 * 4);
    float vs[4] = {v.x, v.y, v.z, v.w};
#pragma unroll
    for (int q = 0; q < 4; ++q) {
      int c = c4 * 4 + q;
      float y = fmaf(vs[q], lst[c], lst[32 + c]);
      x[c] = y > 0.f ? y : 0.f;
    }
  }
  float acc[50];
#pragma unroll
  for (int co = 0; co < 50; ++co) acc[co] = lb[co];
#pragma unroll 4
  for (int c = 0; c < 32; ++c) {
#pragma unroll
    for (int co = 0; co < 50; ++co) acc[co] = fmaf(x[c], lw[c * 50 + co], acc[co]);
  }
  float* o = out + (size_t)i * 50;
#pragma unroll
  for (int co = 0; co < 25; ++co)
    *reinterpret_cast<float2*>(o + co * 2) = make_float2(acc[co * 2], acc[co * 2 + 1]);
}

extern "C" void kernel_launch(void* const* d_in, const int* in_sizes, int n_in,
                              void* d_out, int out_size, void* d_ws, size_t ws_size,
                              hipStream_t stream) {
  const float* feat   = (const float*)d_in[1];
  const int*   nbrF   = (const int*)d_in[2];
  const int*   nbrC   = (const int*)d_in[3];
  const int*   parent = (const int*)d_in[4];
  const int*   offid  = (const int*)d_in[5];
  const float* w_in   = (const float*)d_in[7];
  const float* w_b1   = (const float*)d_in[8];
  const float* w_down = (const float*)d_in[9];
  const float* w_b2   = (const float*)d_in[10];
  const float* w_up   = (const float*)d_in[11];
  const float* w_b3   = (const float*)d_in[12];
  const float* g1v = (const float*)d_in[13], *b1v = (const float*)d_in[14];
  const float* gdv = (const float*)d_in[15], *bdv = (const float*)d_in[16];
  const float* g2v = (const float*)d_in[17], *b2v = (const float*)d_in[18];
  const float* guv = (const float*)d_in[19], *buv = (const float*)d_in[20];
  const float* g3v = (const float*)d_in[21], *b3v = (const float*)d_in[22];
  const float* gov = (const float*)d_in[23], *bov = (const float*)d_in[24];
  const float* w_lin = (const float*)d_in[25];
  const float* b_lin = (const float*)d_in[26];
  float* out = (float*)d_out;

  int N  = in_sizes[4];
  int NC = in_sizes[3] / 27;
  int ntF = (N + 63) / 64, ntC = (NC + 63) / 64;

  size_t szF = (size_t)N * 32;
  size_t szG = (size_t)NC * 64;
  size_t SA = szG > szF ? szG : szF;

  float* ws  = (float*)d_ws;
  float* A   = ws;              // f1 -> g2c -> f3
  float* f2  = A + SA;          // [N,32] skip
  float* gCu = f2 + szF;        // gC [NC,64] -> u [N,32]
  float* sums1 = gCu + SA;      // 64
  float* sumsD = sums1 + 64;    // 64
  float* sums2 = sumsD + 64;    // 128
  float* sumsU = sums2 + 128;   // 128
  float* sums4 = sumsU + 128;   // 64
  float* sums5 = sums4 + 64;    // 64
  int* ccnt = (int*)(sums5 + 64);             // NC (zeroed together with sums)
  int* cent = ccnt + NC;                      // NC*8
  int* segF = cent + (size_t)NC * 8;          // ntF*28
  int* entF = segF + (size_t)ntF * 28;        // ntF*ECAPF
  int* segC = entF + (size_t)ntF * ECAPF;     // ntC*28
  int* entC = segC + (size_t)ntC * 28;        // ntC*ECAPC
  int* segD = entC + (size_t)ntC * ECAPC;     // ntC*9
  int* entD = segD + (size_t)ntC * 9;         // ntC*512
  int* segU = entD + (size_t)ntC * 512;       // ntF*9
  int* entU = segU + (size_t)ntF * 9;         // ntF*64

  hipMemsetAsync(sums1, 0, (512 + NC) * sizeof(float), stream);

  int gridN = (N + BLK - 1) / BLK;
  float invN = 1.f / (float)N, invC = 1.f / (float)NC;

  // rulebooks
  build_fine_k<<<ntF, 64, 0, stream>>>(nbrF, parent, offid, N, ECAPF, segF, entF, segU, entU);
  build_subm_k<<<ntC, 64, 0, stream>>>(nbrC, NC, ECAPC, segC, entC);
  child_scatter_k<<<gridN, BLK, 0, stream>>>(parent, offid, N, ccnt, cent);
  build_down_k<<<ntC, 64, 0, stream>>>(ccnt, cent, NC, segD, entD);

  // conv_in -> f1 (A), stats -> sums1
  conv_in_k<<<gridN, BLK, 0, stream>>>(feat, nbrF, w_in, A, N, sums1);

  // b1 -> f2, stats -> sumsD
  tconv_k<32, 32, 27, false><<<ntF, BLK, 0, stream>>>(
      A, nullptr, segF, entF, ECAPF,
      sums1, g1v, b1v, invN, nullptr, nullptr, nullptr, 0.f,
      w_b1, f2, N, sumsD);

  // down -> gC, stats -> sums2
  tconv_k<32, 64, 8, false><<<ntC, BLK, 0, stream>>>(
      f2, nullptr, segD, entD, 512,
      sumsD, gdv, bdv, invN, nullptr, nullptr, nullptr, 0.f,
      w_down, gCu, NC, sums2);

  // b2 -> g2c (A), stats -> sumsU
  tconv_k<64, 64, 27, false><<<ntC, BLK, 0, stream>>>(
      gCu, nullptr, segC, entC, ECAPC,
      sums2, g2v, b2v, invC, nullptr, nullptr, nullptr, 0.f,
      w_b2, A, NC, sumsU);

  // up -> u (gCu), stats -> sums4
  tconv_k<64, 32, 8, false><<<ntF, BLK, 0, stream>>>(
      A, nullptr, segU, entU, 64,
      sumsU, guv, buv, invC, nullptr, nullptr, nullptr, 0.f,
      w_up, gCu, N, sums4);

  // b3 (concat f2|u) -> f3 (A), stats -> sums5
  tconv_k<64, 32, 27, true><<<ntF, BLK, 0, stream>>>(
      f2, gCu, segF, entF, ECAPF,
      sumsD, g3v, b3v, invN, sums4, g3v + 32, b3v + 32, invN,
      w_b3, A, N, sums5);

  // head
  head_k<<<gridN, BLK, 0, stream>>>(A, sums5, gov, bov, invN, w_lin, b_lin, out, N);
}

// Round 5
// 716.543 us; speedup vs baseline: 1.4709x; 1.4709x over previous
//
#include <hip/hip_runtime.h>

#define EPS_BN 1e-4f
constexpr int BLK = 256;
constexpr int ECAPF = 1792;  // fine subm: worst 27*64 padded
constexpr int ECAPC = 1792;  // coarse subm
constexpr int ECAPD = 544;   // down: 8*64 + 8*3 pad
constexpr int ECAPU = 96;    // up: 64 + 8*3 pad

// entry = (r<<23) | (k<<18) | j ; pad = -1. Groups of 4 share k; first of each
// aligned 4-block is always a real entry (pads only fill group tails).

// ---------- fine rulebook (subm, k-grouped+padded) + up rulebook ----------
__global__ __launch_bounds__(64) void build_fine_k(
    const int* __restrict__ nbr, const int* __restrict__ parent,
    const int* __restrict__ offid, int n,
    int* __restrict__ segP, int* __restrict__ ent,
    int* __restrict__ segPU, int* __restrict__ entu) {
  int T = blockIdx.x, r = threadIdx.x;
  int i = T * 64 + r;
  bool valid = i < n;
  int base = 0;
#pragma unroll 1
  for (int k = 0; k < 27; ++k) {
    int j = valid ? nbr[(size_t)i * 27 + k] : -1;
    bool act = j >= 0;
    unsigned long long mb = __ballot(act);
    int cnt = __popcll(mb);
    int pre = __popcll(mb & ((1ull << r) - 1));
    if (act) ent[(size_t)T * ECAPF + base + pre] = (r << 23) | (k << 18) | j;
    int padded = (cnt + 3) & ~3;
    if (r < padded - cnt) ent[(size_t)T * ECAPF + base + cnt + r] = -1;
    base += padded;
  }
  if (r == 0) segP[T] = base;
  // up rulebook: rows grouped by own offset; j = parent
  int o = valid ? offid[i] : -1;
  int pa = valid ? parent[i] : 0;
  base = 0;
#pragma unroll 1
  for (int oo = 0; oo < 8; ++oo) {
    bool act = (o == oo);
    unsigned long long mb = __ballot(act);
    int cnt = __popcll(mb);
    int pre = __popcll(mb & ((1ull << r) - 1));
    if (act) entu[(size_t)T * ECAPU + base + pre] = (r << 23) | (oo << 18) | pa;
    int padded = (cnt + 3) & ~3;
    if (r < padded - cnt) entu[(size_t)T * ECAPU + base + cnt + r] = -1;
    base += padded;
  }
  if (r == 0) segPU[T] = base;
}

// coarse subm rulebook
__global__ __launch_bounds__(64) void build_subm_k(
    const int* __restrict__ nbr, int n,
    int* __restrict__ segP, int* __restrict__ ent) {
  int T = blockIdx.x, r = threadIdx.x;
  int i = T * 64 + r;
  bool valid = i < n;
  int base = 0;
#pragma unroll 1
  for (int k = 0; k < 27; ++k) {
    int j = valid ? nbr[(size_t)i * 27 + k] : -1;
    bool act = j >= 0;
    unsigned long long mb = __ballot(act);
    int cnt = __popcll(mb);
    int pre = __popcll(mb & ((1ull << r) - 1));
    if (act) ent[(size_t)T * ECAPC + base + pre] = (r << 23) | (k << 18) | j;
    int padded = (cnt + 3) & ~3;
    if (r < padded - cnt) ent[(size_t)T * ECAPC + base + cnt + r] = -1;
    base += padded;
  }
  if (r == 0) segP[T] = base;
}

__global__ __launch_bounds__(BLK) void child_scatter_k(
    const int* __restrict__ parent, const int* __restrict__ offid, int n,
    int* __restrict__ ccnt, int* __restrict__ cent) {
  int i = blockIdx.x * BLK + threadIdx.x;
  if (i >= n) return;
  int p = parent[i];
  int slot = atomicAdd(&ccnt[p], 1);
  cent[p * 8 + slot] = i | (offid[i] << 25);
}

__global__ __launch_bounds__(64) void build_down_k(
    const int* __restrict__ ccnt, const int* __restrict__ cent, int nc,
    int* __restrict__ segd, int* __restrict__ entd) {
  int T = blockIdx.x, r = threadIdx.x;
  int p = T * 64 + r;
  bool valid = p < nc;
  int cn = valid ? ccnt[p] : 0;
  int e[8];
#pragma unroll
  for (int s = 0; s < 8; ++s) e[s] = s < cn ? cent[p * 8 + s] : -1;
  int base = 0;
#pragma unroll 1
  for (int oo = 0; oo < 8; ++oo) {
    int ostart = base;
#pragma unroll
    for (int s = 0; s < 8; ++s) {
      bool act = e[s] >= 0 && (e[s] >> 25) == oo;
      unsigned long long mb = __ballot(act);
      int pre = __popcll(mb & ((1ull << r) - 1));
      if (act) entd[(size_t)T * ECAPD + base + pre] = (r << 23) | (oo << 18) | (e[s] & 0x1FFFFFF);
      base += __popcll(mb);
    }
    int cnt = base - ostart;
    int padded = (cnt + 3) & ~3;
    if (r < padded - cnt) entd[(size_t)T * ECAPD + base + r] = -1;
    base = ostart + padded;
  }
  if (r == 0) segd[T] = base;
}

// ---------- streaming pair-major conv: LDS f32-atomic accumulator, no phase barriers ----------
template <int CI, int CO, bool CAT>
__global__ __launch_bounds__(BLK) void tconv_k(
    const float* __restrict__ inA, const float* __restrict__ inB,
    const int* __restrict__ segP, const int* __restrict__ ent, int ecap,
    const float* __restrict__ sumsA, const float* __restrict__ gA,
    const float* __restrict__ bA, float invA,
    const float* __restrict__ sumsB, const float* __restrict__ gB,
    const float* __restrict__ bB, float invB,
    const float* __restrict__ W, float* __restrict__ out, int n,
    float* __restrict__ osums) {
  constexpr int GO = CO / 16;          // 4 (CO=64) or 2 (CO=32)
  constexpr int AP = CO + 4;
  __shared__ float lacc[64 * AP];
  __shared__ float lst[CAT ? 2 * CI : 4];
  int t = threadIdx.x;
  int T = blockIdx.x;

  if constexpr (CAT) {  // BN finalize for the two halves (fused only here)
    if (t < CI / 2) {
      float mu = sumsA[t] * invA, var = sumsA[CI / 2 + t] * invA - mu * mu;
      float sc = gA[t] / sqrtf(var + EPS_BN);
      lst[t] = sc; lst[CI + t] = bA[t] - mu * sc;
    } else if (t < CI) {
      int c = t - CI / 2;
      float mu = sumsB[c] * invB, var = sumsB[CI / 2 + c] * invB - mu * mu;
      float sc = gB[c] / sqrtf(var + EPS_BN);
      lst[t] = sc; lst[CI + t] = bB[c] - mu * sc;
    }
  }
  for (int idx = t; idx < 64 * AP; idx += BLK) lacc[idx] = 0.f;
  __syncthreads();

  int P = segP[T];
  const int* entT = ent + (size_t)T * ecap;
  int slot = t >> 4, g = (t & 15) * GO;

#pragma unroll 1
  for (int pb = slot * 4; pb < P; pb += 64) {
    int e0 = entT[pb], e1 = entT[pb + 1], e2 = entT[pb + 2], e3 = entT[pb + 3];
    int k = (e0 >> 18) & 31;
    const float* Wk = W + (size_t)k * (CI * CO);
    float acc[4][GO];
#pragma unroll
    for (int pp = 0; pp < 4; ++pp)
#pragma unroll
      for (int b = 0; b < GO; ++b) acc[pp][b] = 0.f;
    int ee[4] = {e0, e1, e2, e3};
#pragma unroll 4
    for (int c4 = 0; c4 < CI / 4; ++c4) {
      int cb = c4 * 4;
      float xs[4][4];
#pragma unroll
      for (int pp = 0; pp < 4; ++pp) {
        float4 x = make_float4(0.f, 0.f, 0.f, 0.f);
        if (ee[pp] >= 0) {
          int j = ee[pp] & 0x3FFFF;
          if constexpr (CAT) {
            x = (cb < CI / 2)
                    ? *reinterpret_cast<const float4*>(inA + (size_t)j * (CI / 2) + cb)
                    : *reinterpret_cast<const float4*>(inB + (size_t)j * (CI / 2) + (cb - CI / 2));
          } else {
            x = *reinterpret_cast<const float4*>(inA + (size_t)j * CI + cb);
          }
        }
        xs[pp][0] = x.x; xs[pp][1] = x.y; xs[pp][2] = x.z; xs[pp][3] = x.w;
        if constexpr (CAT) {
#pragma unroll
          for (int q = 0; q < 4; ++q) {
            float y = fmaf(xs[pp][q], lst[cb + q], lst[CI + cb + q]);
            xs[pp][q] = y > 0.f ? y : 0.f;
          }
        }
      }
#pragma unroll
      for (int q = 0; q < 4; ++q) {
        float wv[GO];
        if constexpr (GO == 4) {
          float4 w4 = *reinterpret_cast<const float4*>(Wk + (cb + q) * CO + g);
          wv[0] = w4.x; wv[1] = w4.y; wv[2] = w4.z; wv[3] = w4.w;
        } else {
          float2 w2 = *reinterpret_cast<const float2*>(Wk + (cb + q) * CO + g);
          wv[0] = w2.x; wv[1] = w2.y;
        }
#pragma unroll
        for (int pp = 0; pp < 4; ++pp)
#pragma unroll
          for (int b = 0; b < GO; ++b)
            acc[pp][b] = fmaf(xs[pp][q], wv[b], acc[pp][b]);
      }
    }
#pragma unroll
    for (int pp = 0; pp < 4; ++pp) {
      if (ee[pp] >= 0) {
        int r = (ee[pp] >> 23) & 63;
        float* ap = &lacc[r * AP + g];
#pragma unroll
        for (int b = 0; b < GO; ++b) atomicAdd(ap + b, acc[pp][b]);  // ds_add_f32
      }
    }
  }
  __syncthreads();

  // epilogue: coalesced store + fused per-channel stats
  for (int idx = t; idx < 64 * (CO / 4); idx += BLK) {
    int r = idx / (CO / 4), c4 = idx - r * (CO / 4);
    int row = T * 64 + r;
    if (row < n)
      *reinterpret_cast<float4*>(out + (size_t)row * CO + c4 * 4) =
          *reinterpret_cast<const float4*>(&lacc[r * AP + c4 * 4]);
  }
  if (t < CO) {
    float s = 0.f, ss = 0.f;
#pragma unroll 4
    for (int r = 0; r < 64; ++r) {
      float x = lacc[r * AP + t];
      s += x; ss = fmaf(x, x, ss);
    }
    atomicAdd(&osums[t], s);
    atomicAdd(&osums[CO + t], ss);
  }
}

// ---------- bnact: y = relu(x*scale + shift), finalize fused ----------
template <int C>
__global__ __launch_bounds__(BLK) void bnact_k(
    const float* __restrict__ in, const float* __restrict__ sums,
    const float* __restrict__ gm, const float* __restrict__ bt, float invn,
    float* __restrict__ outp, int n) {
  __shared__ float lst[2 * C];
  int t = threadIdx.x;
  if (t < C) {
    float mu = sums[t] * invn, var = sums[C + t] * invn - mu * mu;
    float sc = gm[t] / sqrtf(var + EPS_BN);
    lst[t] = sc; lst[C + t] = bt[t] - mu * sc;
  }
  __syncthreads();
  int total = n * (C / 4);
  const float4* in4 = reinterpret_cast<const float4*>(in);
  float4* out4 = reinterpret_cast<float4*>(outp);
  for (int idx = blockIdx.x * BLK + t; idx < total; idx += gridDim.x * BLK) {
    int cb = (idx & (C / 4 - 1)) * 4;
    float4 x = in4[idx];
    float v[4] = {x.x, x.y, x.z, x.w};
#pragma unroll
    for (int q = 0; q < 4; ++q) {
      float y = fmaf(v[q], lst[cb + q], lst[C + cb + q]);
      v[q] = y > 0.f ? y : 0.f;
    }
    out4[idx] = make_float4(v[0], v[1], v[2], v[3]);
  }
}

// ---------------- conv_in: [N,3] x [27,3,32] -> [N,32], fused stats ----------------
__global__ __launch_bounds__(BLK) void conv_in_k(
    const float* __restrict__ feat, const int* __restrict__ nbr,
    const float* __restrict__ W, float* __restrict__ out, int n,
    float* __restrict__ osums) {
  int i = blockIdx.x * BLK + threadIdx.x;
  bool valid = i < n;
  float acc[32];
#pragma unroll
  for (int c = 0; c < 32; ++c) acc[c] = 0.f;
#pragma unroll 1
  for (int k = 0; k < 27; ++k) {
    int j = valid ? nbr[(size_t)i * 27 + k] : -1;
    if (j < 0) continue;
    float x0 = feat[j * 3 + 0], x1 = feat[j * 3 + 1], x2 = feat[j * 3 + 2];
    const float* w0 = W + k * 96;
#pragma unroll
    for (int co = 0; co < 8; ++co) {
      float4 a = *reinterpret_cast<const float4*>(w0 + co * 4);
      float4 b = *reinterpret_cast<const float4*>(w0 + 32 + co * 4);
      float4 cc = *reinterpret_cast<const float4*>(w0 + 64 + co * 4);
      acc[4*co+0] = fmaf(x0, a.x, fmaf(x1, b.x, fmaf(x2, cc.x, acc[4*co+0])));
      acc[4*co+1] = fmaf(x0, a.y, fmaf(x1, b.y, fmaf(x2, cc.y, acc[4*co+1])));
      acc[4*co+2] = fmaf(x0, a.z, fmaf(x1, b.z, fmaf(x2, cc.z, acc[4*co+2])));
      acc[4*co+3] = fmaf(x0, a.w, fmaf(x1, b.w, fmaf(x2, cc.w, acc[4*co+3])));
    }
  }
  if (valid) {
    float* o = out + (size_t)i * 32;
#pragma unroll
    for (int co = 0; co < 8; ++co)
      *reinterpret_cast<float4*>(o + co * 4) = make_float4(acc[4*co], acc[4*co+1], acc[4*co+2], acc[4*co+3]);
  }
  __shared__ float red[2][4][32];
  int w = threadIdx.x >> 6;
#pragma unroll
  for (int c = 0; c < 32; ++c) {
    float v = acc[c], q = acc[c] * acc[c];
#pragma unroll
    for (int off = 32; off; off >>= 1) {
      v += __shfl_down(v, off);
      q += __shfl_down(q, off);
    }
    if ((threadIdx.x & 63) == 0) { red[0][w][c] = v; red[1][w][c] = q; }
  }
  __syncthreads();
  if (threadIdx.x < 64) {
    int kind = threadIdx.x >> 5, c = threadIdx.x & 31;
    float s = red[kind][0][c] + red[kind][1][c] + red[kind][2][c] + red[kind][3][c];
    atomicAdd(&osums[kind * 32 + c], s);
  }
}

// ---------------- head: finalize + bn(f3) @ w_lin + b_lin -> [N,50] ----------------
__global__ __launch_bounds__(BLK) void head_k(
    const float* __restrict__ fin, const float* __restrict__ sums,
    const float* __restrict__ gm, const float* __restrict__ bt, float inv_n,
    const float* __restrict__ Wl, const float* __restrict__ bl,
    float* __restrict__ out, int n) {
  __shared__ float lw[32 * 50];
  __shared__ float lb[52];
  __shared__ float lst[64];
  int t = threadIdx.x;
  if (t < 32) {
    float mu = sums[t] * inv_n, var = sums[32 + t] * inv_n - mu * mu;
    float sc = gm[t] / sqrtf(var + EPS_BN);
    lst[t] = sc; lst[32 + t] = bt[t] - mu * sc;
  }
  for (int idx = t; idx < 1600; idx += BLK) lw[idx] = Wl[idx];
  if (t < 50) lb[t] = bl[t];
  __syncthreads();
  int i = blockIdx.x * BLK + t;
  if (i >= n) return;
  float x[32];
  const float* fj = fin + (size_t)i * 32;
#pragma unroll
  for (int c4 = 0; c4 < 8; ++c4) {
    float4 v = *reinterpret_cast<const float4*>(fj + c4 * 4);
    float vs[4] = {v.x, v.y, v.z, v.w};
#pragma unroll
    for (int q = 0; q < 4; ++q) {
      int c = c4 * 4 + q;
      float y = fmaf(vs[q], lst[c], lst[32 + c]);
      x[c] = y > 0.f ? y : 0.f;
    }
  }
  float acc[50];
#pragma unroll
  for (int co = 0; co < 50; ++co) acc[co] = lb[co];
#pragma unroll 4
  for (int c = 0; c < 32; ++c) {
#pragma unroll
    for (int co = 0; co < 50; ++co) acc[co] = fmaf(x[c], lw[c * 50 + co], acc[co]);
  }
  float* o = out + (size_t)i * 50;
#pragma unroll
  for (int co = 0; co < 25; ++co)
    *reinterpret_cast<float2*>(o + co * 2) = make_float2(acc[co * 2], acc[co * 2 + 1]);
}

extern "C" void kernel_launch(void* const* d_in, const int* in_sizes, int n_in,
                              void* d_out, int out_size, void* d_ws, size_t ws_size,
                              hipStream_t stream) {
  const float* feat   = (const float*)d_in[1];
  const int*   nbrF   = (const int*)d_in[2];
  const int*   nbrC   = (const int*)d_in[3];
  const int*   parent = (const int*)d_in[4];
  const int*   offid  = (const int*)d_in[5];
  const float* w_in   = (const float*)d_in[7];
  const float* w_b1   = (const float*)d_in[8];
  const float* w_down = (const float*)d_in[9];
  const float* w_b2   = (const float*)d_in[10];
  const float* w_up   = (const float*)d_in[11];
  const float* w_b3   = (const float*)d_in[12];
  const float* g1v = (const float*)d_in[13], *b1v = (const float*)d_in[14];
  const float* gdv = (const float*)d_in[15], *bdv = (const float*)d_in[16];
  const float* g2v = (const float*)d_in[17], *b2v = (const float*)d_in[18];
  const float* guv = (const float*)d_in[19], *buv = (const float*)d_in[20];
  const float* g3v = (const float*)d_in[21], *b3v = (const float*)d_in[22];
  const float* gov = (const float*)d_in[23], *bov = (const float*)d_in[24];
  const float* w_lin = (const float*)d_in[25];
  const float* b_lin = (const float*)d_in[26];
  float* out = (float*)d_out;

  int N  = in_sizes[4];
  int NC = in_sizes[3] / 27;
  int ntF = (N + 63) / 64, ntC = (NC + 63) / 64;

  size_t szF = (size_t)N * 32;
  size_t szG = (size_t)NC * 64;
  size_t SA = szG > szF ? szG : szF;

  float* ws  = (float*)d_ws;
  float* S1 = ws;        // f1 / g2c
  float* S2 = S1 + SA;   // a1 / ag
  float* S3 = S2 + SA;   // f2
  float* S4 = S3 + szF;  // a2 / u
  float* S5 = S4 + szF;  // gC / au / f3
  float* sums1 = S5 + SA;       // 64
  float* sumsD = sums1 + 64;    // 64
  float* sums2 = sumsD + 64;    // 128
  float* sumsU = sums2 + 128;   // 128
  float* sums4 = sumsU + 128;   // 64
  float* sums5 = sums4 + 64;    // 64
  int* ccnt = (int*)(sums5 + 64);             // NC
  int* cent = ccnt + NC;                      // NC*8
  int* segPF = cent + (size_t)NC * 8;         // ntF
  int* entF  = segPF + ntF;                   // ntF*ECAPF
  int* segPC = entF + (size_t)ntF * ECAPF;    // ntC
  int* entC  = segPC + ntC;                   // ntC*ECAPC
  int* segPD = entC + (size_t)ntC * ECAPC;    // ntC
  int* entD  = segPD + ntC;                   // ntC*ECAPD
  int* segPU = entD + (size_t)ntC * ECAPD;    // ntF
  int* entU  = segPU + ntF;                   // ntF*ECAPU

  hipMemsetAsync(sums1, 0, (512 + NC) * sizeof(float), stream);

  int gridN = (N + BLK - 1) / BLK;
  int agrid = 1024;
  float invN = 1.f / (float)N, invC = 1.f / (float)NC;

  // rulebooks
  build_fine_k<<<ntF, 64, 0, stream>>>(nbrF, parent, offid, N, segPF, entF, segPU, entU);
  build_subm_k<<<ntC, 64, 0, stream>>>(nbrC, NC, segPC, entC);
  child_scatter_k<<<gridN, BLK, 0, stream>>>(parent, offid, N, ccnt, cent);
  build_down_k<<<ntC, 64, 0, stream>>>(ccnt, cent, NC, segPD, entD);

  // conv_in -> f1(S1), stats -> sums1
  conv_in_k<<<gridN, BLK, 0, stream>>>(feat, nbrF, w_in, S1, N, sums1);
  bnact_k<32><<<agrid, BLK, 0, stream>>>(S1, sums1, g1v, b1v, invN, S2, N);  // a1

  // b1: a1 -> f2(S3), stats -> sumsD
  tconv_k<32, 32, false><<<ntF, BLK, 0, stream>>>(
      S2, nullptr, segPF, entF, ECAPF,
      nullptr, nullptr, nullptr, 0.f, nullptr, nullptr, nullptr, 0.f,
      w_b1, S3, N, sumsD);
  bnact_k<32><<<agrid, BLK, 0, stream>>>(S3, sumsD, gdv, bdv, invN, S4, N);  // a2

  // down: a2 -> gC(S5), stats -> sums2
  tconv_k<32, 64, false><<<ntC, BLK, 0, stream>>>(
      S4, nullptr, segPD, entD, ECAPD,
      nullptr, nullptr, nullptr, 0.f, nullptr, nullptr, nullptr, 0.f,
      w_down, S5, NC, sums2);
  bnact_k<64><<<agrid, BLK, 0, stream>>>(S5, sums2, g2v, b2v, invC, S2, NC); // ag (a1 dead)

  // b2: ag -> g2c(S1, f1 dead), stats -> sumsU
  tconv_k<64, 64, false><<<ntC, BLK, 0, stream>>>(
      S2, nullptr, segPC, entC, ECAPC,
      nullptr, nullptr, nullptr, 0.f, nullptr, nullptr, nullptr, 0.f,
      w_b2, S1, NC, sumsU);
  bnact_k<64><<<agrid, BLK, 0, stream>>>(S1, sumsU, guv, buv, invC, S5, NC); // au (gC dead)

  // up: au -> u(S4, a2 dead), stats -> sums4
  tconv_k<64, 32, false><<<ntF, BLK, 0, stream>>>(
      S5, nullptr, segPU, entU, ECAPU,
      nullptr, nullptr, nullptr, 0.f, nullptr, nullptr, nullptr, 0.f,
      w_up, S4, N, sums4);

  // b3 (concat f2|u, BN fused via lst) -> f3(S5, au dead), stats -> sums5
  tconv_k<64, 32, true><<<ntF, BLK, 0, stream>>>(
      S3, S4, segPF, entF, ECAPF,
      sumsD, g3v, b3v, invN, sums4, g3v + 32, b3v + 32, invN,
      w_b3, S5, N, sums5);

  head_k<<<gridN, BLK, 0, stream>>>(S5, sums5, gov, bov, invN, w_lin, b_lin, out, N);
}

// Round 6
// 586.591 us; speedup vs baseline: 1.7967x; 1.2215x over previous
//
#include <hip/hip_runtime.h>

#define EPS_BN 1e-4f
constexpr int BLK = 256;
constexpr int ECAPC = 1856;  // coarse k-grouped-4 cap (27*64 + 27*3 pad, rounded)
constexpr int NCOPY = 8;     // stats atomic copies

// ---------- fine rulebook: row-major exact, stride 27 ----------
__global__ __launch_bounds__(64) void build_fine_k(
    const int* __restrict__ nbr, int n, int* __restrict__ cnt, int* __restrict__ ent) {
  int i = blockIdx.x * 64 + threadIdx.x;
  if (i >= n) return;
  int c = 0;
  const int* nr = nbr + (size_t)i * 27;
  int* er = ent + (size_t)i * 27;
#pragma unroll 1
  for (int k = 0; k < 27; ++k) {
    int j = nr[k];
    if (j >= 0) er[c++] = (k << 18) | j;
  }
  cnt[i] = c;
}

// ---------- coarse rulebook: k-grouped, padded to groups of 4 ----------
// entry = (r<<23)|(k<<18)|j ; pad = -1 (only group tails)
__global__ __launch_bounds__(64) void build_subm4_k(
    const int* __restrict__ nbr, int n,
    int* __restrict__ segP, int* __restrict__ ent) {
  int T = blockIdx.x, r = threadIdx.x;
  int i = T * 64 + r;
  bool valid = i < n;
  int base = 0;
#pragma unroll 1
  for (int k = 0; k < 27; ++k) {
    int j = valid ? nbr[(size_t)i * 27 + k] : -1;
    bool act = j >= 0;
    unsigned long long mb = __ballot(act);
    int cnt = __popcll(mb);
    int pre = __popcll(mb & ((1ull << r) - 1));
    if (act) ent[(size_t)T * ECAPC + base + pre] = (r << 23) | (k << 18) | j;
    int padded = (cnt + 3) & ~3;
    if (r < padded - cnt) ent[(size_t)T * ECAPC + base + cnt + r] = -1;
    base += padded;
  }
  if (r == 0) segP[T] = base;
}

__global__ __launch_bounds__(BLK) void child_scatter_k(
    const int* __restrict__ parent, const int* __restrict__ offid, int n,
    int* __restrict__ ccnt, int* __restrict__ cent) {
  int i = blockIdx.x * BLK + threadIdx.x;
  if (i >= n) return;
  int p = parent[i];
  int slot = atomicAdd(&ccnt[p], 1);
  cent[p * 8 + slot] = i | (offid[i] << 25);
}

// ---------- Type A: output-stationary register-acc gather (no barriers/atomics in loop) ----------
// MODE 0: fine rulebook (ent stride 27, cnt[] per row)
// MODE 1: down (ent=cent stride 8, cnt=ccnt)
// MODE 2: up (k=offid[row], j=parent[row], 1 entry)
template <int CI, int CO, int MODE>
__global__ __launch_bounds__(BLK) void tconvA_k(
    const float* __restrict__ in, const int* __restrict__ ent, const int* __restrict__ cnt,
    const int* __restrict__ parent, const int* __restrict__ offid,
    const float* __restrict__ W, float* __restrict__ out, int n,
    float* __restrict__ osums) {
  constexpr int LANES = CO / 4, SLOTS = BLK / LANES, RPS = 64 / SLOTS;
  __shared__ float red[2 * CO];
  int t = threadIdx.x;
  for (int idx = t; idx < 2 * CO; idx += BLK) red[idx] = 0.f;
  __syncthreads();
  int slot = t / LANES, lane = t % LANES, g = lane * 4;
  int T = blockIdx.x;
  float ssum[4] = {0, 0, 0, 0}, ssq[4] = {0, 0, 0, 0};
#pragma unroll 1
  for (int rr = 0; rr < RPS; ++rr) {
    int row = T * 64 + slot * RPS + rr;
    bool vrow = row < n;
    float a0 = 0.f, a1 = 0.f, a2 = 0.f, a3 = 0.f;
    int ec = 0;
    if (vrow) ec = (MODE == 2) ? 1 : cnt[row];
#pragma unroll 1
    for (int e = 0; e < ec; ++e) {
      int k, j;
      if constexpr (MODE == 0) {
        int v = ent[(size_t)row * 27 + e];
        k = (v >> 18) & 31; j = v & 0x3FFFF;
      } else if constexpr (MODE == 1) {
        int v = ent[(size_t)row * 8 + e];
        k = v >> 25; j = v & 0x1FFFFFF;
      } else {
        k = offid[row]; j = parent[row];
      }
      const float* Wk = W + (size_t)k * (CI * CO) + g;
      const float* xr = in + (size_t)j * CI;
#pragma unroll
      for (int h = 0; h < CI / 32; ++h) {
        float4 xv[8];
#pragma unroll
        for (int c4 = 0; c4 < 8; ++c4)
          xv[c4] = *reinterpret_cast<const float4*>(xr + h * 32 + c4 * 4);
#pragma unroll
        for (int c4 = 0; c4 < 8; ++c4) {
          float xs[4] = {xv[c4].x, xv[c4].y, xv[c4].z, xv[c4].w};
#pragma unroll
          for (int q = 0; q < 4; ++q) {
            float4 wv = *reinterpret_cast<const float4*>(Wk + (size_t)(h * 32 + c4 * 4 + q) * CO);
            a0 = fmaf(xs[q], wv.x, a0);
            a1 = fmaf(xs[q], wv.y, a1);
            a2 = fmaf(xs[q], wv.z, a2);
            a3 = fmaf(xs[q], wv.w, a3);
          }
        }
      }
    }
    if (vrow)
      *reinterpret_cast<float4*>(out + (size_t)row * CO + g) = make_float4(a0, a1, a2, a3);
    ssum[0] += a0; ssum[1] += a1; ssum[2] += a2; ssum[3] += a3;
    ssq[0] = fmaf(a0, a0, ssq[0]); ssq[1] = fmaf(a1, a1, ssq[1]);
    ssq[2] = fmaf(a2, a2, ssq[2]); ssq[3] = fmaf(a3, a3, ssq[3]);
  }
#pragma unroll
  for (int q = 0; q < 4; ++q) {
    atomicAdd(&red[g + q], ssum[q]);
    atomicAdd(&red[CO + g + q], ssq[q]);
  }
  __syncthreads();
  int copy = blockIdx.x & (NCOPY - 1);
  if (t < 2 * CO) atomicAdd(&osums[copy * 2 * CO + t], red[t]);
}

// ---------- Type B: k-grouped-4 stream + LDS f32-atomic accumulator (coarse b2) ----------
template <int CI, int CO>
__global__ __launch_bounds__(BLK) void tconvB_k(
    const float* __restrict__ in, const int* __restrict__ segP,
    const int* __restrict__ ent, int ecap,
    const float* __restrict__ W, float* __restrict__ out, int n,
    float* __restrict__ osums) {
  constexpr int GO = CO / 16;
  constexpr int AP = CO + 4;
  __shared__ float lacc[64 * AP];
  int t = threadIdx.x, T = blockIdx.x;
  for (int idx = t; idx < 64 * AP; idx += BLK) lacc[idx] = 0.f;
  __syncthreads();
  int P = segP[T];
  const int* entT = ent + (size_t)T * ecap;
  int slot = t >> 4, g = (t & 15) * GO;
#pragma unroll 1
  for (int pb = slot * 4; pb < P; pb += 64) {
    int ee[4] = {entT[pb], entT[pb + 1], entT[pb + 2], entT[pb + 3]};
    int k = (ee[0] >> 18) & 31;
    const float* Wk = W + (size_t)k * (CI * CO);
    float acc[4][GO];
#pragma unroll
    for (int pp = 0; pp < 4; ++pp)
#pragma unroll
      for (int b = 0; b < GO; ++b) acc[pp][b] = 0.f;
#pragma unroll 4
    for (int c4 = 0; c4 < CI / 4; ++c4) {
      int cb = c4 * 4;
      float xs[4][4];
#pragma unroll
      for (int pp = 0; pp < 4; ++pp) {
        float4 x = make_float4(0.f, 0.f, 0.f, 0.f);
        if (ee[pp] >= 0) {
          int j = ee[pp] & 0x3FFFF;
          x = *reinterpret_cast<const float4*>(in + (size_t)j * CI + cb);
        }
        xs[pp][0] = x.x; xs[pp][1] = x.y; xs[pp][2] = x.z; xs[pp][3] = x.w;
      }
#pragma unroll
      for (int q = 0; q < 4; ++q) {
        float4 w4 = *reinterpret_cast<const float4*>(Wk + (size_t)(cb + q) * CO + g);
        float wv[4] = {w4.x, w4.y, w4.z, w4.w};
#pragma unroll
        for (int pp = 0; pp < 4; ++pp)
#pragma unroll
          for (int b = 0; b < GO; ++b)
            acc[pp][b] = fmaf(xs[pp][q], wv[b], acc[pp][b]);
      }
    }
#pragma unroll
    for (int pp = 0; pp < 4; ++pp) {
      if (ee[pp] >= 0) {
        int r = (ee[pp] >> 23) & 63;
        float* ap = &lacc[r * AP + g];
#pragma unroll
        for (int b = 0; b < GO; ++b) atomicAdd(ap + b, acc[pp][b]);
      }
    }
  }
  __syncthreads();
  for (int idx = t; idx < 64 * (CO / 4); idx += BLK) {
    int r = idx / (CO / 4), c4 = idx - r * (CO / 4);
    int row = T * 64 + r;
    if (row < n)
      *reinterpret_cast<float4*>(out + (size_t)row * CO + c4 * 4) =
          *reinterpret_cast<const float4*>(&lacc[r * AP + c4 * 4]);
  }
  int copy = blockIdx.x & (NCOPY - 1);
  if (t < CO) {
    float s = 0.f, ss = 0.f;
#pragma unroll 4
    for (int r = 0; r < 64; ++r) {
      float x = lacc[r * AP + t];
      s += x; ss = fmaf(x, x, ss);
    }
    atomicAdd(&osums[copy * 2 * CO + t], s);
    atomicAdd(&osums[copy * 2 * CO + CO + t], ss);
  }
}

// ---------- bnact: finalize(8 copies) + relu(x*scale+shift) ----------
template <int C>
__global__ __launch_bounds__(BLK) void bnact_k(
    const float* __restrict__ in, const float* __restrict__ sums,
    const float* __restrict__ gm, const float* __restrict__ bt, float invn,
    float* __restrict__ outp, int n) {
  __shared__ float lst[2 * C];
  int t = threadIdx.x;
  if (t < C) {
    float s = 0.f, q = 0.f;
#pragma unroll
    for (int cp = 0; cp < NCOPY; ++cp) { s += sums[cp * 2 * C + t]; q += sums[cp * 2 * C + C + t]; }
    float mu = s * invn, var = q * invn - mu * mu;
    float sc = gm[t] / sqrtf(var + EPS_BN);
    lst[t] = sc; lst[C + t] = bt[t] - mu * sc;
  }
  __syncthreads();
  int total = n * (C / 4);
  const float4* in4 = reinterpret_cast<const float4*>(in);
  float4* out4 = reinterpret_cast<float4*>(outp);
  for (int idx = blockIdx.x * BLK + t; idx < total; idx += gridDim.x * BLK) {
    int cb = (idx & (C / 4 - 1)) * 4;
    float4 x = in4[idx];
    float v[4] = {x.x, x.y, x.z, x.w};
#pragma unroll
    for (int q = 0; q < 4; ++q) {
      float y = fmaf(v[q], lst[cb + q], lst[C + cb + q]);
      v[q] = y > 0.f ? y : 0.f;
    }
    out4[idx] = make_float4(v[0], v[1], v[2], v[3]);
  }
}

// ---------- bncat: concat(bn(f2), bn(u)) -> acat [N,64] ----------
__global__ __launch_bounds__(BLK) void bncat_k(
    const float* __restrict__ fa, const float* __restrict__ sA,
    const float* __restrict__ gA, const float* __restrict__ bA,
    const float* __restrict__ fb, const float* __restrict__ sB,
    const float* __restrict__ gB, const float* __restrict__ bB,
    float invn, float* __restrict__ acat, int n) {
  __shared__ float lst[128];
  int t = threadIdx.x;
  if (t < 64) {
    int half = t >> 5, c = t & 31;
    const float* ss = half ? sB : sA;
    const float* gg = half ? gB : gA;
    const float* bb = half ? bB : bA;
    float s = 0.f, q = 0.f;
#pragma unroll
    for (int cp = 0; cp < NCOPY; ++cp) { s += ss[cp * 64 + c]; q += ss[cp * 64 + 32 + c]; }
    float mu = s * invn, var = q * invn - mu * mu;
    float sc = gg[c] / sqrtf(var + EPS_BN);
    lst[half * 64 + c] = sc; lst[half * 64 + 32 + c] = bb[c] - mu * sc;
  }
  __syncthreads();
  int total = n * 16;
  for (int idx = blockIdx.x * BLK + t; idx < total; idx += gridDim.x * BLK) {
    int row = idx >> 4, c4 = idx & 15;
    int half = c4 >> 3, cc = (c4 & 7) * 4;
    const float* src = half ? fb : fa;
    float4 x = *reinterpret_cast<const float4*>(src + (size_t)row * 32 + cc);
    const float* L = lst + half * 64;
    float v[4] = {x.x, x.y, x.z, x.w};
#pragma unroll
    for (int q = 0; q < 4; ++q) {
      float y = fmaf(v[q], L[cc + q], L[32 + cc + q]);
      v[q] = y > 0.f ? y : 0.f;
    }
    *reinterpret_cast<float4*>(acat + (size_t)row * 64 + c4 * 4) = make_float4(v[0], v[1], v[2], v[3]);
  }
}

// ---------------- conv_in: [N,3] x [27,3,32] -> [N,32], fused stats ----------------
__global__ __launch_bounds__(BLK) void conv_in_k(
    const float* __restrict__ feat, const int* __restrict__ nbr,
    const float* __restrict__ W, float* __restrict__ out, int n,
    float* __restrict__ osums) {
  int i = blockIdx.x * BLK + threadIdx.x;
  bool valid = i < n;
  float acc[32];
#pragma unroll
  for (int c = 0; c < 32; ++c) acc[c] = 0.f;
#pragma unroll 1
  for (int k = 0; k < 27; ++k) {
    int j = valid ? nbr[(size_t)i * 27 + k] : -1;
    if (j < 0) continue;
    float x0 = feat[j * 3 + 0], x1 = feat[j * 3 + 1], x2 = feat[j * 3 + 2];
    const float* w0 = W + k * 96;
#pragma unroll
    for (int co = 0; co < 8; ++co) {
      float4 a = *reinterpret_cast<const float4*>(w0 + co * 4);
      float4 b = *reinterpret_cast<const float4*>(w0 + 32 + co * 4);
      float4 cc = *reinterpret_cast<const float4*>(w0 + 64 + co * 4);
      acc[4*co+0] = fmaf(x0, a.x, fmaf(x1, b.x, fmaf(x2, cc.x, acc[4*co+0])));
      acc[4*co+1] = fmaf(x0, a.y, fmaf(x1, b.y, fmaf(x2, cc.y, acc[4*co+1])));
      acc[4*co+2] = fmaf(x0, a.z, fmaf(x1, b.z, fmaf(x2, cc.z, acc[4*co+2])));
      acc[4*co+3] = fmaf(x0, a.w, fmaf(x1, b.w, fmaf(x2, cc.w, acc[4*co+3])));
    }
  }
  if (valid) {
    float* o = out + (size_t)i * 32;
#pragma unroll
    for (int co = 0; co < 8; ++co)
      *reinterpret_cast<float4*>(o + co * 4) = make_float4(acc[4*co], acc[4*co+1], acc[4*co+2], acc[4*co+3]);
  }
  __shared__ float red[2][4][32];
  int w = threadIdx.x >> 6;
#pragma unroll
  for (int c = 0; c < 32; ++c) {
    float v = acc[c], q = acc[c] * acc[c];
#pragma unroll
    for (int off = 32; off; off >>= 1) {
      v += __shfl_down(v, off);
      q += __shfl_down(q, off);
    }
    if ((threadIdx.x & 63) == 0) { red[0][w][c] = v; red[1][w][c] = q; }
  }
  __syncthreads();
  if (threadIdx.x < 64) {
    int kind = threadIdx.x >> 5, c = threadIdx.x & 31;
    float s = red[kind][0][c] + red[kind][1][c] + red[kind][2][c] + red[kind][3][c];
    atomicAdd(&osums[(blockIdx.x & (NCOPY - 1)) * 64 + kind * 32 + c], s);
  }
}

// ---------------- head: finalize(8 copies) + bn @ w_lin + b_lin -> [N,50] ----------------
__global__ __launch_bounds__(BLK) void head_k(
    const float* __restrict__ fin, const float* __restrict__ sums,
    const float* __restrict__ gm, const float* __restrict__ bt, float inv_n,
    const float* __restrict__ Wl, const float* __restrict__ bl,
    float* __restrict__ out, int n) {
  __shared__ float lw[32 * 50];
  __shared__ float lb[52];
  __shared__ float lst[64];
  int t = threadIdx.x;
  if (t < 32) {
    float s = 0.f, q = 0.f;
#pragma unroll
    for (int cp = 0; cp < NCOPY; ++cp) { s += sums[cp * 64 + t]; q += sums[cp * 64 + 32 + t]; }
    float mu = s * inv_n, var = q * inv_n - mu * mu;
    float sc = gm[t] / sqrtf(var + EPS_BN);
    lst[t] = sc; lst[32 + t] = bt[t] - mu * sc;
  }
  for (int idx = t; idx < 1600; idx += BLK) lw[idx] = Wl[idx];
  if (t < 50) lb[t] = bl[t];
  __syncthreads();
  int i = blockIdx.x * BLK + t;
  if (i >= n) return;
  float x[32];
  const float* fj = fin + (size_t)i * 32;
#pragma unroll
  for (int c4 = 0; c4 < 8; ++c4) {
    float4 v = *reinterpret_cast<const float4*>(fj + c4 * 4);
    float vs[4] = {v.x, v.y, v.z, v.w};
#pragma unroll
    for (int q = 0; q < 4; ++q) {
      int c = c4 * 4 + q;
      float y = fmaf(vs[q], lst[c], lst[32 + c]);
      x[c] = y > 0.f ? y : 0.f;
    }
  }
  float acc[50];
#pragma unroll
  for (int co = 0; co < 50; ++co) acc[co] = lb[co];
#pragma unroll 4
  for (int c = 0; c < 32; ++c) {
#pragma unroll
    for (int co = 0; co < 50; ++co) acc[co] = fmaf(x[c], lw[c * 50 + co], acc[co]);
  }
  float* o = out + (size_t)i * 50;
#pragma unroll
  for (int co = 0; co < 25; ++co)
    *reinterpret_cast<float2*>(o + co * 2) = make_float2(acc[co * 2], acc[co * 2 + 1]);
}

extern "C" void kernel_launch(void* const* d_in, const int* in_sizes, int n_in,
                              void* d_out, int out_size, void* d_ws, size_t ws_size,
                              hipStream_t stream) {
  const float* feat   = (const float*)d_in[1];
  const int*   nbrF   = (const int*)d_in[2];
  const int*   nbrC   = (const int*)d_in[3];
  const int*   parent = (const int*)d_in[4];
  const int*   offid  = (const int*)d_in[5];
  const float* w_in   = (const float*)d_in[7];
  const float* w_b1   = (const float*)d_in[8];
  const float* w_down = (const float*)d_in[9];
  const float* w_b2   = (const float*)d_in[10];
  const float* w_up   = (const float*)d_in[11];
  const float* w_b3   = (const float*)d_in[12];
  const float* g1v = (const float*)d_in[13], *b1v = (const float*)d_in[14];
  const float* gdv = (const float*)d_in[15], *bdv = (const float*)d_in[16];
  const float* g2v = (const float*)d_in[17], *b2v = (const float*)d_in[18];
  const float* guv = (const float*)d_in[19], *buv = (const float*)d_in[20];
  const float* g3v = (const float*)d_in[21], *b3v = (const float*)d_in[22];
  const float* gov = (const float*)d_in[23], *bov = (const float*)d_in[24];
  const float* w_lin = (const float*)d_in[25];
  const float* b_lin = (const float*)d_in[26];
  float* out = (float*)d_out;

  int N  = in_sizes[4];
  int NC = in_sizes[3] / 27;
  int ntF = (N + 63) / 64, ntC = (NC + 63) / 64;

  size_t szF = (size_t)N * 32;
  size_t szG = (size_t)NC * 64;
  size_t SB  = (size_t)N * 64;  // >= szF, szG, acat

  float* ws = (float*)d_ws;
  float* S1 = ws;          // f1 [N,32] -> g2c [NC,64]
  float* S2 = S1 + SB;     // a1 -> ag -> acat [N,64]
  float* S3 = S2 + SB;     // f2 [N,32] -> f3 [N,32]
  float* S4 = S3 + szF;    // a2 [N,32] -> u [N,32]
  float* S5 = S4 + szF;    // gC [NC,64] -> au [NC,64]
  float* sums1 = S5 + szG;           // 8*64
  float* sumsD = sums1 + 8 * 64;     // 8*64
  float* sums2 = sumsD + 8 * 64;     // 8*128
  float* sumsU = sums2 + 8 * 128;    // 8*128
  float* sums4 = sumsU + 8 * 128;    // 8*64
  float* sums5 = sums4 + 8 * 64;     // 8*64
  int* ccnt = (int*)(sums5 + 8 * 64);         // NC
  int* cent = ccnt + NC;                      // NC*8
  int* cntF = cent + (size_t)NC * 8;          // N
  int* entF = cntF + N;                       // N*27
  int* segPC = entF + (size_t)N * 27;         // ntC
  int* entC  = segPC + ntC;                   // ntC*ECAPC

  hipMemsetAsync(sums1, 0, (4096 + NC) * sizeof(float), stream);

  int gridN = (N + BLK - 1) / BLK;
  int agrid = 1024;
  float invN = 1.f / (float)N, invC = 1.f / (float)NC;

  // rulebooks
  build_fine_k<<<ntF, 64, 0, stream>>>(nbrF, N, cntF, entF);
  build_subm4_k<<<ntC, 64, 0, stream>>>(nbrC, NC, segPC, entC);
  child_scatter_k<<<gridN, BLK, 0, stream>>>(parent, offid, N, ccnt, cent);

  // conv_in -> f1(S1), stats -> sums1
  conv_in_k<<<gridN, BLK, 0, stream>>>(feat, nbrF, w_in, S1, N, sums1);
  bnact_k<32><<<agrid, BLK, 0, stream>>>(S1, sums1, g1v, b1v, invN, S2, N);   // a1

  // b1: a1 -> f2(S3), stats -> sumsD
  tconvA_k<32, 32, 0><<<ntF, BLK, 0, stream>>>(
      S2, entF, cntF, nullptr, nullptr, w_b1, S3, N, sumsD);
  bnact_k<32><<<agrid, BLK, 0, stream>>>(S3, sumsD, gdv, bdv, invN, S4, N);   // a2

  // down: a2 -> gC(S5), stats -> sums2
  tconvA_k<32, 64, 1><<<ntC, BLK, 0, stream>>>(
      S4, cent, ccnt, nullptr, nullptr, w_down, S5, NC, sums2);
  bnact_k<64><<<agrid, BLK, 0, stream>>>(S5, sums2, g2v, b2v, invC, S2, NC);  // ag (a1 dead)

  // b2: ag -> g2c(S1, f1 dead), stats -> sumsU
  tconvB_k<64, 64><<<ntC, BLK, 0, stream>>>(
      S2, segPC, entC, ECAPC, w_b2, S1, NC, sumsU);
  bnact_k<64><<<agrid, BLK, 0, stream>>>(S1, sumsU, guv, buv, invC, S5, NC);  // au (gC dead)

  // up: au -> u(S4, a2 dead), stats -> sums4
  tconvA_k<64, 32, 2><<<ntF, BLK, 0, stream>>>(
      S5, nullptr, nullptr, parent, offid, w_up, S4, N, sums4);

  // bncat: (bn(f2)|bn(u)) -> acat(S2, ag dead)
  bncat_k<<<agrid, BLK, 0, stream>>>(
      S3, sumsD, g3v, b3v, S4, sums4, g3v + 32, b3v + 32, invN, S2, N);

  // b3: acat -> f3(S3, f2 dead), stats -> sums5
  tconvA_k<64, 32, 0><<<ntF, BLK, 0, stream>>>(
      S2, entF, cntF, nullptr, nullptr, w_b3, S3, N, sums5);

  head_k<<<gridN, BLK, 0, stream>>>(S3, sums5, gov, bov, invN, w_lin, b_lin, out, N);
}